// Round 1
// baseline (1819.762 us; speedup 1.0000x reference)
//
#include <hip/hip_runtime.h>
#include <hip/hip_bf16.h>
#include <math.h>

#define B_  64
#define A_  26
#define L_  384
#define D_  512
#define K_  18
#define LP1 385   // L_ + 1

// ---------------- conv weight transpose: (D,A,K) -> (A*K, D) ----------------
__global__ void transpose_w_kernel(const float* __restrict__ w, float* __restrict__ wt) {
    int o = blockIdx.x * blockDim.x + threadIdx.x;   // o = r*D + d
    int total = A_ * K_ * D_;
    if (o >= total) return;
    int d = o % D_;
    int r = o / D_;                                   // r = a*K + k
    wt[o] = w[(size_t)d * (A_ * K_) + r];
}

// ---------------- conv1d -> e (B, L, D) ----------------
__global__ __launch_bounds__(512) void conv_kernel(const float* __restrict__ x,     // (B, A, L)
                                                   const float* __restrict__ wt,    // (A*K, D)
                                                   const float* __restrict__ bias,  // (D,)
                                                   float* __restrict__ e) {         // (B, L, D)
    const int TL = 32;
    const int XW = TL + K_ - 1;     // 49
    int l0 = blockIdx.x * TL;
    int b  = blockIdx.y;
    int d  = threadIdx.x;           // 512 threads, one per output channel
    __shared__ float xs[A_][XW];
    for (int idx = threadIdx.x; idx < A_ * XW; idx += 512) {
        int a = idx / XW, p = idx % XW;
        int g = l0 - (K_ - 1) / 2 + p;  // l0 - 8 + p
        xs[a][p] = (g >= 0 && g < L_) ? x[((size_t)b * A_ + a) * L_ + g] : 0.0f;
    }
    __syncthreads();
    float acc[TL];
#pragma unroll
    for (int l = 0; l < TL; ++l) acc[l] = 0.0f;
#pragma unroll 1
    for (int a = 0; a < A_; ++a) {
        float xr[XW];
#pragma unroll
        for (int p = 0; p < XW; ++p) xr[p] = xs[a][p];
        const float* wrow = wt + (size_t)(a * K_) * D_ + d;
#pragma unroll
        for (int k = 0; k < K_; ++k) {
            float w = wrow[(size_t)k * D_];
#pragma unroll
            for (int l = 0; l < TL; ++l)
                acc[l] = fmaf(xr[k + l], w, acc[l]);
        }
    }
    float bv = bias[d];
#pragma unroll
    for (int l = 0; l < TL; ++l)
        e[((size_t)b * L_ + (l0 + l)) * D_ + d] = acc[l] + bv;
}

// ---------------- sim[b,l,m] = dot(e[b,l,:], e[0,m,:]) ----------------
__global__ __launch_bounds__(256) void sim_kernel(const float* __restrict__ e, float* __restrict__ sim) {
    int b  = blockIdx.z;
    int m0 = blockIdx.x * 32;
    int l0 = blockIdx.y * 32;
    __shared__ float As[32][33];
    __shared__ float Bs[32][33];
    int tid = threadIdx.x;
    int tx = tid & 15, ty = tid >> 4;
    const float* ea = e + (size_t)b * L_ * D_;
    const float* e0 = e;   // batch 0
    float acc00 = 0.f, acc01 = 0.f, acc10 = 0.f, acc11 = 0.f;
    int lrow = tid >> 3;          // 0..31
    int lcol = (tid & 7) << 2;    // 0,4,..,28
    for (int kc = 0; kc < D_; kc += 32) {
        float4 av = *(const float4*)(ea + (size_t)(l0 + lrow) * D_ + kc + lcol);
        float4 bv = *(const float4*)(e0 + (size_t)(m0 + lrow) * D_ + kc + lcol);
        As[lrow][lcol + 0] = av.x; As[lrow][lcol + 1] = av.y;
        As[lrow][lcol + 2] = av.z; As[lrow][lcol + 3] = av.w;
        Bs[lrow][lcol + 0] = bv.x; Bs[lrow][lcol + 1] = bv.y;
        Bs[lrow][lcol + 2] = bv.z; Bs[lrow][lcol + 3] = bv.w;
        __syncthreads();
#pragma unroll
        for (int kk = 0; kk < 32; ++kk) {
            float a0 = As[2 * ty][kk], a1 = As[2 * ty + 1][kk];
            float b0 = Bs[2 * tx][kk], b1 = Bs[2 * tx + 1][kk];
            acc00 = fmaf(a0, b0, acc00); acc01 = fmaf(a0, b1, acc01);
            acc10 = fmaf(a1, b0, acc10); acc11 = fmaf(a1, b1, acc11);
        }
        __syncthreads();
    }
    float* sp = sim + ((size_t)b * L_ + l0) * L_ + m0;
    sp[(2 * ty + 0) * L_ + 2 * tx + 0] = acc00;
    sp[(2 * ty + 0) * L_ + 2 * tx + 1] = acc01;
    sp[(2 * ty + 1) * L_ + 2 * tx + 0] = acc10;
    sp[(2 * ty + 1) * L_ + 2 * tx + 1] = acc11;
}

// ---------------- NW forward: V (L+1)x(L+1) per batch ----------------
// V[i,j] = sim[i-1,j-1] + smoothmax3(V[i-1,j-1], V[i-1,j], V[i,j-1])   (g=0, t=1)
__global__ __launch_bounds__(384) void nw_fwd_kernel(const float* __restrict__ sim, float* __restrict__ V) {
    int b = blockIdx.x;
    const float* sb = sim + (size_t)b * L_ * L_;
    float* Vb = V + (size_t)b * LP1 * LP1;
    __shared__ float ring[3][400];
    for (int idx = threadIdx.x; idx < 3 * 400; idx += 384)
        ((float*)ring)[idx] = 0.0f;   // boundary V[i,0]=V[0,j]=0 lives here forever
    __syncthreads();
    int i = threadIdx.x + 1;          // 1..384
    for (int d = 2; d <= 2 * L_; ++d) {
        float*       cur = ring[d % 3];
        const float* p1  = ring[(d + 2) % 3];  // diag d-1
        const float* p2  = ring[(d + 1) % 3];  // diag d-2
        int j = d - i;
        if (j >= 1 && j <= L_) {
            float dg = p2[i - 1];   // V[i-1,j-1]
            float up = p1[i - 1];   // V[i-1,j]
            float lf = p1[i];       // V[i,j-1]
            float s  = sb[(size_t)(i - 1) * L_ + (j - 1)];
            float mx = fmaxf(dg, fmaxf(up, lf));
            float v  = s + mx + __logf(__expf(dg - mx) + __expf(up - mx) + __expf(lf - mx));
            cur[i] = v;
            Vb[(size_t)i * LP1 + j] = v;
        }
        __syncthreads();
    }
}

// ---------------- NW backward: align[b,i-1,j-1] = E[i,j] ----------------
// E[i,j] = [i==li && j==lj]
//        + E[i+1,j+1]*exp(V[i,j] - (V[i+1,j+1]-sim[i,j]))
//        + E[i+1,j  ]*exp(V[i,j] - (V[i+1,j  ]-sim[i,j-1]))
//        + E[i,  j+1]*exp(V[i,j] - (V[i,  j+1]-sim[i-1,j]))
__global__ __launch_bounds__(384) void nw_bwd_kernel(const float* __restrict__ sim,
                                                     const float* __restrict__ V,
                                                     const int* __restrict__ shapes,
                                                     float* __restrict__ align_) {
    int b = blockIdx.x;
    const float* sb = sim + (size_t)b * L_ * L_;
    const float* Vb = V + (size_t)b * LP1 * LP1;
    float* ab = align_ + (size_t)b * L_ * L_;
    int li = shapes[2 * b + 0];
    int lj = shapes[2 * b + 1];
    li = min(max(li, 0), L_);
    lj = min(max(lj, 0), L_);
    __shared__ float ring[3][400];
    for (int idx = threadIdx.x; idx < 3 * 400; idx += 384)
        ((float*)ring)[idx] = 0.0f;
    __syncthreads();
    int i = threadIdx.x + 1;          // 1..384
    for (int d = 2 * L_; d >= 2; --d) {
        float*       cur = ring[d % 3];
        const float* p1  = ring[(d + 1) % 3];  // diag d+1
        const float* p2  = ring[(d + 2) % 3];  // diag d+2
        int j = d - i;
        if (j >= 1 && j <= L_) {
            float vij  = Vb[(size_t)i * LP1 + j];
            float eacc = (i == li && j == lj) ? 1.0f : 0.0f;
            if (i < L_ && j < L_)
                eacc += p2[i + 1] * __expf(vij - (Vb[(size_t)(i + 1) * LP1 + (j + 1)] - sb[(size_t)i * L_ + j]));
            if (i < L_)
                eacc += p1[i + 1] * __expf(vij - (Vb[(size_t)(i + 1) * LP1 + j] - sb[(size_t)i * L_ + (j - 1)]));
            if (j < L_)
                eacc += p1[i] * __expf(vij - (Vb[(size_t)i * LP1 + (j + 1)] - sb[(size_t)(i - 1) * L_ + j]));
            cur[i] = eacc;
            ab[(size_t)(i - 1) * L_ + (j - 1)] = eacc;
        }
        __syncthreads();
    }
}

// ---------------- consensus[j,a] = (1/B) sum_n sum_i matrices[n,a,i]*align[n,i,j] ----------------
__global__ __launch_bounds__(256) void consensus_kernel(const float* __restrict__ x,      // (B,A,L)
                                                        const float* __restrict__ align_, // (B,L,L)
                                                        float* __restrict__ cons) {       // (L,A)
    int n  = blockIdx.y;
    int j0 = blockIdx.x * 64;
    __shared__ float ms[A_][L_];    // 39.9 KB: matrices[n] staged
    for (int idx = threadIdx.x; idx < A_ * L_; idx += 256)
        ((float*)ms)[idx] = x[(size_t)n * A_ * L_ + idx];
    __syncthreads();
    int jl = threadIdx.x & 63;
    int g  = threadIdx.x >> 6;      // 0..3
    int a0 = g * 7;                 // 0,7,14,21
    int na = (a0 + 7 <= A_) ? 7 : (A_ - a0);   // 7,7,7,5
    int j  = j0 + jl;
    float acc[7] = {0.f, 0.f, 0.f, 0.f, 0.f, 0.f, 0.f};
    const float* acol = align_ + (size_t)n * L_ * L_ + j;
    for (int i = 0; i < L_; ++i) {
        float al = acol[(size_t)i * L_];
#pragma unroll
        for (int t = 0; t < 7; ++t)
            if (t < na) acc[t] = fmaf(al, ms[a0 + t][i], acc[t]);
    }
    for (int t = 0; t < na; ++t)
        atomicAdd(&cons[(size_t)j * A_ + a0 + t], acc[t] * (1.0f / B_));
}

// ---------------- out[n,i,a] = sum_j cons[j,a] * align[n,i,j] ----------------
__global__ __launch_bounds__(256) void out_kernel(const float* __restrict__ align_,
                                                  const float* __restrict__ cons,
                                                  float* __restrict__ out) {
    int n  = blockIdx.y;
    int i0 = blockIdx.x * 32;
    __shared__ float cs[L_][A_];        // 40.0 KB
    __shared__ float as_[32][L_ + 1];   // 49.3 KB (pad: break 384-stride bank alias)
    for (int idx = threadIdx.x; idx < L_ * A_; idx += 256)
        ((float*)cs)[idx] = cons[idx];
    for (int idx = threadIdx.x; idx < 32 * L_; idx += 256) {
        int r = idx / L_, c = idx % L_;
        as_[r][c] = align_[((size_t)n * L_ + i0 + r) * L_ + c];
    }
    __syncthreads();
    for (int o = threadIdx.x; o < 32 * A_; o += 256) {
        int il = o / A_, a = o % A_;
        float s = 0.f;
        for (int jj = 0; jj < L_; ++jj)
            s = fmaf(as_[il][jj], cs[jj][a], s);
        out[((size_t)n * L_ + i0 + il) * A_ + a] = s;
    }
}

extern "C" void kernel_launch(void* const* d_in, const int* in_sizes, int n_in,
                              void* d_out, int out_size, void* d_ws, size_t ws_size,
                              hipStream_t stream) {
    const float* matrices = (const float*)d_in[0];   // (B,A,L) f32
    const int*   shapes   = (const int*)d_in[1];     // (B,2) i32
    const float* conv_w   = (const float*)d_in[2];   // (D,A,K) f32
    const float* conv_b   = (const float*)d_in[3];   // (D,) f32
    float* out = (float*)d_out;                      // (B,L,A) f32

    float* ws     = (float*)d_ws;
    float* e      = ws;                                   // B*L*D   = 12,582,912
    float* sim    = e     + (size_t)B_ * L_ * D_;         // B*L*L   =  9,437,184
    float* V      = sim   + (size_t)B_ * L_ * L_;         // B*385^2 =  9,486,400
    float* align_ = V     + (size_t)B_ * LP1 * LP1;       // B*L*L   =  9,437,184
    float* wt     = align_ + (size_t)B_ * L_ * L_;        // A*K*D   =    239,616
    float* cons   = wt    + (size_t)A_ * K_ * D_;         // L*A     =      9,984

    transpose_w_kernel<<<(A_ * K_ * D_ + 255) / 256, 256, 0, stream>>>(conv_w, wt);
    conv_kernel<<<dim3(L_ / 32, B_), 512, 0, stream>>>(matrices, wt, conv_b, e);
    sim_kernel<<<dim3(L_ / 32, L_ / 32, B_), 256, 0, stream>>>(e, sim);
    nw_fwd_kernel<<<B_, 384, 0, stream>>>(sim, V);
    nw_bwd_kernel<<<B_, 384, 0, stream>>>(sim, V, shapes, align_);
    hipMemsetAsync(cons, 0, (size_t)L_ * A_ * sizeof(float), stream);
    consensus_kernel<<<dim3(L_ / 64, B_), 256, 0, stream>>>(matrices, align_, cons);
    out_kernel<<<dim3(L_ / 32, B_), 256, 0, stream>>>(align_, cons, out);
}

// Round 2
// 1371.173 us; speedup vs baseline: 1.3272x; 1.3272x over previous
//
#include <hip/hip_runtime.h>
#include <hip/hip_bf16.h>
#include <math.h>

#define B_  64
#define A_  26
#define L_  384
#define D_  512
#define K_  18
#define LP1 385   // L_ + 1
#define CF  64    // forward chunk (columns per superstep)
#define CB  32    // backward chunk

// ---------------- conv weight transpose: (D,A,K) -> (A*K, D) ----------------
__global__ void transpose_w_kernel(const float* __restrict__ w, float* __restrict__ wt) {
    int o = blockIdx.x * blockDim.x + threadIdx.x;   // o = r*D + d
    int total = A_ * K_ * D_;
    if (o >= total) return;
    int d = o % D_;
    int r = o / D_;                                   // r = a*K + k
    wt[o] = w[(size_t)d * (A_ * K_) + r];
}

// ---------------- conv1d -> e (B, L, D) ----------------
__global__ __launch_bounds__(512) void conv_kernel(const float* __restrict__ x,     // (B, A, L)
                                                   const float* __restrict__ wt,    // (A*K, D)
                                                   const float* __restrict__ bias,  // (D,)
                                                   float* __restrict__ e) {         // (B, L, D)
    const int TL = 32;
    const int XW = TL + K_ - 1;     // 49
    int l0 = blockIdx.x * TL;
    int b  = blockIdx.y;
    int d  = threadIdx.x;           // 512 threads, one per output channel
    __shared__ float xs[A_][XW];
    for (int idx = threadIdx.x; idx < A_ * XW; idx += 512) {
        int a = idx / XW, p = idx % XW;
        int g = l0 - (K_ - 1) / 2 + p;  // l0 - 8 + p
        xs[a][p] = (g >= 0 && g < L_) ? x[((size_t)b * A_ + a) * L_ + g] : 0.0f;
    }
    __syncthreads();
    float acc[TL];
#pragma unroll
    for (int l = 0; l < TL; ++l) acc[l] = 0.0f;
#pragma unroll 1
    for (int a = 0; a < A_; ++a) {
        float xr[XW];
#pragma unroll
        for (int p = 0; p < XW; ++p) xr[p] = xs[a][p];
        const float* wrow = wt + (size_t)(a * K_) * D_ + d;
#pragma unroll
        for (int k = 0; k < K_; ++k) {
            float w = wrow[(size_t)k * D_];
#pragma unroll
            for (int l = 0; l < TL; ++l)
                acc[l] = fmaf(xr[k + l], w, acc[l]);
        }
    }
    float bv = bias[d];
#pragma unroll
    for (int l = 0; l < TL; ++l)
        e[((size_t)b * L_ + (l0 + l)) * D_ + d] = acc[l] + bv;
}

// ---------------- sim[b,l,m] = dot(e[b,l,:], e[0,m,:]) ----------------
__global__ __launch_bounds__(256) void sim_kernel(const float* __restrict__ e, float* __restrict__ sim) {
    int b  = blockIdx.z;
    int m0 = blockIdx.x * 32;
    int l0 = blockIdx.y * 32;
    __shared__ float As[32][33];
    __shared__ float Bs[32][33];
    int tid = threadIdx.x;
    int tx = tid & 15, ty = tid >> 4;
    const float* ea = e + (size_t)b * L_ * D_;
    const float* e0 = e;   // batch 0
    float acc00 = 0.f, acc01 = 0.f, acc10 = 0.f, acc11 = 0.f;
    int lrow = tid >> 3;          // 0..31
    int lcol = (tid & 7) << 2;    // 0,4,..,28
    for (int kc = 0; kc < D_; kc += 32) {
        float4 av = *(const float4*)(ea + (size_t)(l0 + lrow) * D_ + kc + lcol);
        float4 bv = *(const float4*)(e0 + (size_t)(m0 + lrow) * D_ + kc + lcol);
        As[lrow][lcol + 0] = av.x; As[lrow][lcol + 1] = av.y;
        As[lrow][lcol + 2] = av.z; As[lrow][lcol + 3] = av.w;
        Bs[lrow][lcol + 0] = bv.x; Bs[lrow][lcol + 1] = bv.y;
        Bs[lrow][lcol + 2] = bv.z; Bs[lrow][lcol + 3] = bv.w;
        __syncthreads();
#pragma unroll
        for (int kk = 0; kk < 32; ++kk) {
            float a0 = As[2 * ty][kk], a1 = As[2 * ty + 1][kk];
            float b0 = Bs[2 * tx][kk], b1 = Bs[2 * tx + 1][kk];
            acc00 = fmaf(a0, b0, acc00); acc01 = fmaf(a0, b1, acc01);
            acc10 = fmaf(a1, b0, acc10); acc11 = fmaf(a1, b1, acc11);
        }
        __syncthreads();
    }
    float* sp = sim + ((size_t)b * L_ + l0) * L_ + m0;
    sp[(2 * ty + 0) * L_ + 2 * tx + 0] = acc00;
    sp[(2 * ty + 0) * L_ + 2 * tx + 1] = acc01;
    sp[(2 * ty + 1) * L_ + 2 * tx + 0] = acc10;
    sp[(2 * ty + 1) * L_ + 2 * tx + 1] = acc11;
}

// ---------------- NW forward: wave-skewed pipeline ----------------
// V[i,j] = sim[i-1,j-1] + smoothmax3(V[i-1,j-1], V[i-1,j], V[i,j-1])   (g=0, t=1)
// Lane l of wave w owns row i = 64w+1+l. At step t it computes column
// j = j0+1+t-l. Recurrence inputs: own register (left), __shfl_up of
// neighbor's last value (up), previous step's shuffled value (diag).
// Strip boundary rows flow through LDS `bot` (parity double-buffered).
__global__ __launch_bounds__(384, 1) void nw_fwd_kernel(const float* __restrict__ sim, float* __restrict__ V) {
    int b = blockIdx.x;
    const float* sb = sim + (size_t)b * L_ * L_;
    float* Vb = V + (size_t)b * LP1 * LP1;
    __shared__ float simt[6][64][66];        // stride 66: skewed read (l+t)%32 -> 2-way, free
    __shared__ float bot[2][6][CF + 1];      // [parity][wave][0..CF], idx0 = carry V[64w+64, j0]
    int tid = threadIdx.x;
    int w = tid >> 6, l = tid & 63;
    int i = (w << 6) + 1 + l;                // row 1..384
    float left = 0.0f;                       // V[i, 0] = 0 boundary
    float* Vrow = Vb + (size_t)i * LP1;
    const float* srow0 = sb + (size_t)(i - 1) * L_;
    const int nch = L_ / CF;                 // 6
    for (int T = 0; T < nch + 5; ++T) {
        int c = T - w;
        if (c >= 0 && c < nch) {
            int j0 = c * CF;
            // stage sim[i-1, j0 .. j0+CF-1] into own LDS row (aligned float4)
            float* myl = simt[w][l];
            const float* srow = srow0 + j0;
#pragma unroll
            for (int q = 0; q < CF / 4; ++q) {
                float4 v = *(const float4*)(srow + 4 * q);
                myl[4 * q + 0] = v.x; myl[4 * q + 1] = v.y;
                myl[4 * q + 2] = v.z; myl[4 * q + 3] = v.w;
            }
            const float* botprev = bot[c & 1][(w == 0) ? 0 : (w - 1)];
            float* botcur = bot[c & 1][w];
            if (l == 63) botcur[0] = left;   // carry V[64w+64, j0]
            float cur = left;
            float prev_nb = (l == 0) ? ((w == 0) ? 0.f : botprev[0]) : 0.f;
#pragma unroll 2
            for (int t = 0; t < CF + 63; ++t) {
                float nb = __shfl_up(cur, 1);                    // V[i-1, j]
                if (l == 0) nb = (w == 0) ? 0.f : botprev[min(t + 1, CF)];
                if (t >= l && t < l + CF) {
                    float dg = prev_nb, up = nb, lf = cur;
                    float s = myl[t - l];                        // sim[i-1, j-1]
                    float mx = fmaxf(dg, fmaxf(up, lf));
                    float v = s + mx + __logf(__expf(dg - mx) + __expf(up - mx) + __expf(lf - mx));
                    cur = v;
                    Vrow[j0 + 1 + t - l] = v;
                    if (l == 63) botcur[t - 62] = v;             // publish bottom row
                }
                prev_nb = nb;
            }
            left = cur;                                          // V[i, j0+CF]
        }
        __syncthreads();
    }
}

// ---------------- NW backward: mirrored wave-skewed pipeline ----------------
// E[i,j] = [i==li && j==lj]
//        + E[i+1,j+1]*exp(V[i,j] - V[i+1,j+1] + sim[i,j])
//        + E[i+1,j  ]*exp(V[i,j] - V[i+1,j  ] + sim[i,j-1])
//        + E[i,  j+1]*exp(V[i,j] - V[i,  j+1] + sim[i-1,j])
// Wave 5 (bottom strip) starts first; columns sweep right-to-left.
__global__ __launch_bounds__(384, 1) void nw_bwd_kernel(const float* __restrict__ sim,
                                                        const float* __restrict__ V,
                                                        const int* __restrict__ shapes,
                                                        float* __restrict__ align_) {
    int b = blockIdx.x;
    const float* sb = sim + (size_t)b * L_ * L_;
    const float* Vb = V + (size_t)b * LP1 * LP1;
    float* ab = align_ + (size_t)b * L_ * L_;
    int li = min(max(shapes[2 * b + 0], 0), L_);
    int lj = min(max(shapes[2 * b + 1], 0), L_);
    __shared__ float Vt[6][65][34];          // Vt[w][rl][q] = V[64w+1+rl, colbase+q]
    __shared__ float St[6][65][34];          // St[w][rl][q] = sim[64w+rl,  colbase+q]
    __shared__ float top[2][6][CB + 1];      // [parity][wave][0..CB], idxCB = carry E[64w+1, jhi+1]
    int tid = threadIdx.x;
    int w = tid >> 6, l = tid & 63;
    int i = (w << 6) + 1 + l;                // row 1..384
    // zero the extra LDS rows once (guarded-away reads must stay finite)
    for (int idx = tid; idx < 6 * 34; idx += 384) {
        Vt[idx / 34][64][idx % 34] = 0.f;
        St[idx / 34][64][idx % 34] = 0.f;
    }
    __syncthreads();
    float cur = 0.0f;                        // E[i, 385] = 0 boundary
    float* arow = ab + (size_t)(i - 1) * L_ - 1;     // arow[j] = align[i-1, j-1]
    const int nch = L_ / CB;                 // 12
    const float* VtL = Vt[w][l];
    const float* VtU = Vt[w][l + 1];
    const float* StL = St[w][l];
    const float* StU = St[w][l + 1];
    for (int T = 0; T < nch + 5; ++T) {
        int c = T - (5 - w);
        if (c >= 0 && c < nch) {
            int jhi = L_ - c * CB;           // chunk columns [jhi-CB+1 .. jhi]
            int colbase = jhi - CB;          // staged cols colbase .. colbase+CB+1
            {
                const float* vr = Vb + (size_t)i * LP1 + colbase;
                const float* sr = sb + (size_t)((w << 6) + l) * L_ + colbase;
                float* dV = Vt[w][l];
                float* dS = St[w][l];
#pragma unroll
                for (int q = 0; q < CB + 2; ++q) {
                    int col = colbase + q;
                    dV[q] = (col <= L_) ? vr[q] : 0.f;       // V cols 0..384
                    dS[q] = (col < L_) ? sr[q] : 0.f;        // sim cols 0..383
                }
                if (l == 63) {                               // extra top row rl=64
                    int vrow = i + 1;                        // 64w+65
                    int srw = (w << 6) + 64;
                    const float* vr2 = Vb + (size_t)vrow * LP1 + colbase;
                    const float* sr2 = sb + (size_t)srw * L_ + colbase;
                    float* dV2 = Vt[w][64];
                    float* dS2 = St[w][64];
#pragma unroll
                    for (int q = 0; q < CB + 2; ++q) {
                        int col = colbase + q;
                        dV2[q] = (vrow <= L_ && col <= L_) ? vr2[q] : 0.f;
                        dS2[q] = (srw < L_ && col < L_) ? sr2[q] : 0.f;
                    }
                }
            }
            const float* topnext = top[c & 1][(w == 5) ? 5 : (w + 1)];
            float* topcur = top[c & 1][w];
            if (l == 0) topcur[CB] = cur;    // carry E[64w+1, jhi+1]
            float prev_nb = (l == 63) ? ((w == 5) ? 0.f : topnext[CB]) : 0.f;
#pragma unroll 2
            for (int t = 0; t < CB + 63; ++t) {
                float nb = __shfl_down(cur, 1);              // E[i+1, j]
                if (l == 63) nb = (w == 5) ? 0.f : topnext[max(CB - 1 - t, 0)];
                int qj = CB + 63 - t - l;                    // j - colbase
                if (qj >= 1 && qj <= CB) {
                    int j = colbase + qj;
                    float vij = VtL[qj];
                    float eacc = (i == li && j == lj) ? 1.0f : 0.0f;
                    float td = __expf(vij - VtU[qj + 1] + StU[qj]) * prev_nb;
                    float tu = __expf(vij - VtU[qj]     + StU[qj - 1]) * nb;
                    float tl = __expf(vij - VtL[qj + 1] + StL[qj]) * cur;
                    if (i < L_ && j < L_) eacc += td;
                    if (i < L_)           eacc += tu;
                    if (j < L_)           eacc += tl;
                    cur = eacc;
                    arow[j] = eacc;
                    if (l == 0) topcur[CB + 62 - t] = eacc;  // publish top row
                }
                prev_nb = nb;
            }
        }
        __syncthreads();
    }
}

// ---------------- consensus[j,a] = (1/B) sum_n sum_i matrices[n,a,i]*align[n,i,j] ----------------
__global__ __launch_bounds__(256) void consensus_kernel(const float* __restrict__ x,      // (B,A,L)
                                                        const float* __restrict__ align_, // (B,L,L)
                                                        float* __restrict__ cons) {       // (L,A)
    int n  = blockIdx.y;
    int j0 = blockIdx.x * 64;
    __shared__ float ms[A_][L_];    // 39.9 KB: matrices[n] staged
    for (int idx = threadIdx.x; idx < A_ * L_; idx += 256)
        ((float*)ms)[idx] = x[(size_t)n * A_ * L_ + idx];
    __syncthreads();
    int jl = threadIdx.x & 63;
    int g  = threadIdx.x >> 6;      // 0..3
    int a0 = g * 7;                 // 0,7,14,21
    int na = (a0 + 7 <= A_) ? 7 : (A_ - a0);   // 7,7,7,5
    int j  = j0 + jl;
    float acc[7] = {0.f, 0.f, 0.f, 0.f, 0.f, 0.f, 0.f};
    const float* acol = align_ + (size_t)n * L_ * L_ + j;
    for (int i = 0; i < L_; ++i) {
        float al = acol[(size_t)i * L_];
#pragma unroll
        for (int t = 0; t < 7; ++t)
            if (t < na) acc[t] = fmaf(al, ms[a0 + t][i], acc[t]);
    }
    for (int t = 0; t < na; ++t)
        atomicAdd(&cons[(size_t)j * A_ + a0 + t], acc[t] * (1.0f / B_));
}

// ---------------- out[n,i,a] = sum_j cons[j,a] * align[n,i,j] ----------------
__global__ __launch_bounds__(256) void out_kernel(const float* __restrict__ align_,
                                                  const float* __restrict__ cons,
                                                  float* __restrict__ out) {
    int n  = blockIdx.y;
    int i0 = blockIdx.x * 32;
    __shared__ float cs[L_][A_];        // 40.0 KB
    __shared__ float as_[32][L_ + 1];   // 49.3 KB (pad: break 384-stride bank alias)
    for (int idx = threadIdx.x; idx < L_ * A_; idx += 256)
        ((float*)cs)[idx] = cons[idx];
    for (int idx = threadIdx.x; idx < 32 * L_; idx += 256) {
        int r = idx / L_, c = idx % L_;
        as_[r][c] = align_[((size_t)n * L_ + i0 + r) * L_ + c];
    }
    __syncthreads();
    for (int o = threadIdx.x; o < 32 * A_; o += 256) {
        int il = o / A_, a = o % A_;
        float s = 0.f;
        for (int jj = 0; jj < L_; ++jj)
            s = fmaf(as_[il][jj], cs[jj][a], s);
        out[((size_t)n * L_ + i0 + il) * A_ + a] = s;
    }
}

extern "C" void kernel_launch(void* const* d_in, const int* in_sizes, int n_in,
                              void* d_out, int out_size, void* d_ws, size_t ws_size,
                              hipStream_t stream) {
    const float* matrices = (const float*)d_in[0];   // (B,A,L) f32
    const int*   shapes   = (const int*)d_in[1];     // (B,2) i32
    const float* conv_w   = (const float*)d_in[2];   // (D,A,K) f32
    const float* conv_b   = (const float*)d_in[3];   // (D,) f32
    float* out = (float*)d_out;                      // (B,L,A) f32

    float* ws     = (float*)d_ws;
    float* e      = ws;                                   // B*L*D   = 12,582,912
    float* sim    = e     + (size_t)B_ * L_ * D_;         // B*L*L   =  9,437,184
    float* V      = sim   + (size_t)B_ * L_ * L_;         // B*385^2 =  9,486,400
    float* align_ = V     + (size_t)B_ * LP1 * LP1;       // B*L*L   =  9,437,184
    float* wt     = align_ + (size_t)B_ * L_ * L_;        // A*K*D   =    239,616
    float* cons   = wt    + (size_t)A_ * K_ * D_;         // L*A     =      9,984

    transpose_w_kernel<<<(A_ * K_ * D_ + 255) / 256, 256, 0, stream>>>(conv_w, wt);
    conv_kernel<<<dim3(L_ / 32, B_), 512, 0, stream>>>(matrices, wt, conv_b, e);
    sim_kernel<<<dim3(L_ / 32, L_ / 32, B_), 256, 0, stream>>>(e, sim);
    nw_fwd_kernel<<<B_, 384, 0, stream>>>(sim, V);
    nw_bwd_kernel<<<B_, 384, 0, stream>>>(sim, V, shapes, align_);
    hipMemsetAsync(cons, 0, (size_t)L_ * A_ * sizeof(float), stream);
    consensus_kernel<<<dim3(L_ / 64, B_), 256, 0, stream>>>(matrices, align_, cons);
    out_kernel<<<dim3(L_ / 32, B_), 256, 0, stream>>>(align_, cons, out);
}